// Round 9
// baseline (352.577 us; speedup 1.0000x reference)
//
#include <hip/hip_runtime.h>

#define N      2048
#define HALO   10            // sweeps fused per launch
#define SWP    10
#define WX     128           // window width (16 threads x 8 cols)
#define WY     64            // window rows  (16 bands x 4 rows)
#define TX     108           // output tile width
#define TY     44            // output tile height
#define NTX    19            // last tile clamped; overlap writes identical values
#define NTY    47
#define NTHR   256
#define NB     16            // bands of 4 rows
#define PS     132           // LDS boundary row stride (words)

// ---- init: x = exp(-50*((X-0.5)^2 + (Y-0.5)^2)) ----
__global__ __launch_bounds__(256) void jm_init(const float4* __restrict__ X,
                                               const float4* __restrict__ Y,
                                               float4* __restrict__ out) {
    int t = blockIdx.x * 256 + threadIdx.x;
    float4 x = X[t];
    float4 y = Y[t];
    float4 r;
    r.x = expf(-50.f * ((x.x - 0.5f) * (x.x - 0.5f) + (y.x - 0.5f) * (y.x - 0.5f)));
    r.y = expf(-50.f * ((x.y - 0.5f) * (x.y - 0.5f) + (y.y - 0.5f) * (y.y - 0.5f)));
    r.z = expf(-50.f * ((x.z - 0.5f) * (x.z - 0.5f) + (y.z - 0.5f) * (y.z - 0.5f)));
    r.w = expf(-50.f * ((x.w - 0.5f) * (x.w - 0.5f) + (y.w - 0.5f) * (y.w - 0.5f)));
    out[t] = r;
}

// Sweep engine: each thread owns a 4x8 patch in VGPRs. Single 16.9 KB LDS slab
// for band-boundary rows, 2 barriers/sweep (small LDS -> ~8 blocks/CU resident,
// barrier stalls overlap across blocks). Window-edge cells absorb deterministic
// wrong-band shuffle values; contamination advances 1 cell/sweep and stored
// cells sit at window distance >= HALO, so they are exact.
template<bool INTERIOR>
__device__ __forceinline__ void run_sweeps(float4 (&pA)[4], float4 (&pB)[4],
                                           float* __restrict__ bnd,
                                           const int g, const int c,
                                           const float* __restrict__ f,
                                           const float* __restrict__ rm) {
    const int co = 8 * c;
    const int wT = (NB + g) * PS + co;      // my top row slot
    const int wB = g * PS + co;             // my bottom row slot
    const int rU = (g - 1) * PS + co;       // bbot[g-1]  (g>0)
    const int rD = (NB + g + 1) * PS + co;  // btop[g+1]  (g<NB-1)

    for (int s = 0; s < SWP; ++s) {
        *(float4*)(bnd + wT)     = pA[0];
        *(float4*)(bnd + wT + 4) = pB[0];
        *(float4*)(bnd + wB)     = pA[3];
        *(float4*)(bnd + wB + 4) = pB[3];
        __syncthreads();
        float4 z = make_float4(0.f, 0.f, 0.f, 0.f);
        float4 upA = z, upB = z, dnA = z, dnB = z;
        if (g > 0)      { upA = *(const float4*)(bnd + rU); upB = *(const float4*)(bnd + rU + 4); }
        if (g < NB - 1) { dnA = *(const float4*)(bnd + rD); dnB = *(const float4*)(bnd + rD + 4); }
        __syncthreads();                    // reads done; next sweep may overwrite

        float4 poA = upA, poB = upB;        // old row above current
        #pragma unroll
        for (int k = 0; k < 4; ++k) {
            float4 cA = pA[k], cB = pB[k];
            float4 dA = (k < 3) ? pA[k + 1] : dnA;   // old values
            float4 dB = (k < 3) ? pB[k + 1] : dnB;
            float lf = __shfl_up(cB.w, 1);           // wrong-band at c==0: window edge only
            float rg = __shfl_down(cA.x, 1);         // wrong-band at c==15: window edge only
            float4 sA, sB;
            sA.x = poA.x + dA.x + lf   + cA.y;
            sA.y = poA.y + dA.y + cA.x + cA.z;
            sA.z = poA.z + dA.z + cA.y + cA.w;
            sA.w = poA.w + dA.w + cA.z + cB.x;
            sB.x = poB.x + dB.x + cA.w + cB.y;
            sB.y = poB.y + dB.y + cB.x + cB.z;
            sB.z = poB.z + dB.z + cB.y + cB.w;
            sB.w = poB.w + dB.w + cB.z + rg;
            float4 nA, nB;
            if (INTERIOR) {
                nA.x = sA.x * 0.25f; nA.y = sA.y * 0.25f;
                nA.z = sA.z * 0.25f; nA.w = sA.w * 0.25f;
                nB.x = sB.x * 0.25f; nB.y = sB.y * 0.25f;
                nB.z = sB.z * 0.25f; nB.w = sB.w * 0.25f;
            } else {
                float r = rm[k];
                nA.x = sA.x * (f[0] * r); nA.y = sA.y * (f[1] * r);
                nA.z = sA.z * (f[2] * r); nA.w = sA.w * (f[3] * r);
                nB.x = sB.x * (f[4] * r); nB.y = sB.y * (f[5] * r);
                nB.z = sB.z * (f[6] * r); nB.w = sB.w * (f[7] * r);
            }
            pA[k] = nA; pB[k] = nB;
            poA = cA; poB = cB;
        }
    }
}

__global__ __launch_bounds__(NTHR) void jm_sweep(const float* __restrict__ in,
                                                 float* __restrict__ out) {
    __shared__ float bnd[2 * NB * PS];   // 16.9 KB: rows [0..15]=bbot, [16..31]=btop
    const int bx = blockIdx.x % NTX;
    const int by = blockIdx.x / NTX;
    const int ox = (bx < NTX - 1) ? bx * TX : (N - TX);
    const int oy = (by < NTY - 1) ? by * TY : (N - TY);
    const int gx0 = ox - HALO, gy0 = oy - HALO;
    const int t = threadIdx.x;
    const int c = t & 15;                // column chunk (8 cols)
    const int g = t >> 4;                // band
    const int colb = gx0 + 8 * c;        // global col of patch col 0

    // boundary-path mask factors
    float f[8];
    #pragma unroll
    for (int j = 0; j < 8; ++j)
        f[j] = (colb + j >= 1 && colb + j <= N - 2) ? 0.25f : 0.f;
    float rm[4];
    #pragma unroll
    for (int k = 0; k < 4; ++k) {
        int gr = gy0 + 4 * g + k;
        rm[k] = (gr >= 1 && gr <= N - 2) ? 1.f : 0.f;
    }

    // ---- load 4x8 patch (out-of-domain -> 0) ----
    float4 pA[4], pB[4];
    #pragma unroll
    for (int k = 0; k < 4; ++k) {
        int gr = gy0 + 4 * g + k;
        float4 a = make_float4(0.f, 0.f, 0.f, 0.f);
        float4 b = make_float4(0.f, 0.f, 0.f, 0.f);
        if (gr >= 0 && gr < N) {
            const float* row = in + (long)gr * N;
            if (colb >= 0 && colb + 7 < N) {
                a = *(const float4*)(row + colb);
                b = *(const float4*)(row + colb + 4);
            } else {
                float v[8];
                #pragma unroll
                for (int j = 0; j < 8; ++j)
                    v[j] = (colb + j >= 0 && colb + j < N) ? row[colb + j] : 0.f;
                a = make_float4(v[0], v[1], v[2], v[3]);
                b = make_float4(v[4], v[5], v[6], v[7]);
            }
        }
        pA[k] = a; pB[k] = b;
    }

    // whole window strictly inside the domain ring? (block-uniform branch)
    const bool interior = (gx0 >= 1) && (gx0 + WX - 1 <= N - 2) &&
                          (gy0 >= 1) && (gy0 + WY - 1 <= N - 2);
    if (interior) run_sweeps<true >(pA, pB, bnd, g, c, f, rm);
    else          run_sweeps<false>(pA, pB, bnd, g, c, f, rm);

    // ---- store valid interior: window rows 10..53, cols 10..117 ----
    #pragma unroll
    for (int k = 0; k < 4; ++k) {
        int w = 4 * g + k;
        if (w >= HALO && w < WY - HALO) {
            float* orow = out + (long)(gy0 + w) * N;
            if (c >= 2 && c <= 13) {
                *(float4*)(orow + colb)     = pA[k];
                *(float4*)(orow + colb + 4) = pB[k];
            } else if (c == 1) {          // cols 8..15 -> keep 10..15
                float2 v; v.x = pA[k].z; v.y = pA[k].w;
                *(float2*)(orow + gx0 + 10) = v;
                *(float4*)(orow + gx0 + 12) = pB[k];
            } else if (c == 14) {         // cols 112..119 -> keep 112..117
                *(float4*)(orow + colb) = pA[k];
                float2 v; v.x = pB[k].x; v.y = pB[k].y;
                *(float2*)(orow + gx0 + 116) = v;
            }
        }
    }
}

extern "C" void kernel_launch(void* const* d_in, const int* in_sizes, int n_in,
                              void* d_out, int out_size, void* d_ws, size_t ws_size,
                              hipStream_t stream) {
    const float* X = (const float*)d_in[0];
    const float* Y = (const float*)d_in[1];

    float* a = (float*)d_out;   // ping
    float* b = (float*)d_ws;    // pong (16 MiB of workspace)

    jm_init<<<(N * N / 4) / 256, 256, 0, stream>>>((const float4*)X, (const float4*)Y,
                                                   (float4*)a);

    // 100 sweeps = 10 launches x 10 fused sweeps; even -> final lands in d_out
    for (int it = 0; it < 10; ++it) {
        jm_sweep<<<NTX * NTY, NTHR, 0, stream>>>(a, b);
        float* tp = a; a = b; b = tp;
    }
}

// Round 10
// 263.482 us; speedup vs baseline: 1.3381x; 1.3381x over previous
//
#include <hip/hip_runtime.h>

#define N      2048
#define HALO   10            // sweeps fused per launch
#define SWP    10
#define WX     128           // window width (16 threads x 8 cols)
#define WY     64            // window rows  (16 bands x 4 rows)
#define TX     108           // output tile width
#define TY     44            // output tile height
#define NTX    19            // last tile clamped; overlap writes identical values
#define NTY    47
#define NTHR   256
#define NB     16            // bands of 4 rows
#define PS     132           // LDS boundary row stride (words)

// ---- init: x = exp(-50*((X-0.5)^2 + (Y-0.5)^2)) ----
__global__ __launch_bounds__(256) void jm_init(const float4* __restrict__ X,
                                               const float4* __restrict__ Y,
                                               float4* __restrict__ out) {
    int t = blockIdx.x * 256 + threadIdx.x;
    float4 x = X[t];
    float4 y = Y[t];
    float4 r;
    r.x = expf(-50.f * ((x.x - 0.5f) * (x.x - 0.5f) + (y.x - 0.5f) * (y.x - 0.5f)));
    r.y = expf(-50.f * ((x.y - 0.5f) * (x.y - 0.5f) + (y.y - 0.5f) * (y.y - 0.5f)));
    r.z = expf(-50.f * ((x.z - 0.5f) * (x.z - 0.5f) + (y.z - 0.5f) * (y.z - 0.5f)));
    r.w = expf(-50.f * ((x.w - 0.5f) * (x.w - 0.5f) + (y.w - 0.5f) * (y.w - 0.5f)));
    out[t] = r;
}

// Register-resident fused sweeps: each thread owns a 4x8 patch in VGPRs.
// LDS holds only band-boundary rows (old top/bottom of each band per sweep).
// lf/rg neighbors via wave shuffles. Contamination advances 1 cell/sweep,
// stored cells sit at window distance >= HALO -> exact after HALO sweeps.
__global__ __launch_bounds__(NTHR) void jm_sweep(const float* __restrict__ in,
                                                 float* __restrict__ out) {
    __shared__ float bnd[2 * NB * PS];   // rows [0..15]=bbot(g), [16..31]=btop(g)
    const int bx = blockIdx.x % NTX;
    const int by = blockIdx.x / NTX;
    const int ox = (bx < NTX - 1) ? bx * TX : (N - TX);
    const int oy = (by < NTY - 1) ? by * TY : (N - TY);
    const int gx0 = ox - HALO, gy0 = oy - HALO;
    const int t = threadIdx.x;
    const int c = t & 15;                // column chunk (8 cols)
    const int g = t >> 4;                // band
    const int colb = gx0 + 8 * c;        // global col of patch col 0

    // column mask factors (0.25 interior, 0 on/outside boundary) and row masks
    float f[8];
    #pragma unroll
    for (int j = 0; j < 8; ++j)
        f[j] = (colb + j >= 1 && colb + j <= N - 2) ? 0.25f : 0.f;
    float rm[4];
    #pragma unroll
    for (int k = 0; k < 4; ++k) {
        int gr = gy0 + 4 * g + k;
        rm[k] = (gr >= 1 && gr <= N - 2) ? 1.f : 0.f;
    }

    // ---- load 4x8 patch (out-of-domain -> 0) ----
    float4 pA[4], pB[4];
    #pragma unroll
    for (int k = 0; k < 4; ++k) {
        int gr = gy0 + 4 * g + k;
        float4 a = make_float4(0.f, 0.f, 0.f, 0.f);
        float4 b = make_float4(0.f, 0.f, 0.f, 0.f);
        if (gr >= 0 && gr < N) {
            const float* row = in + (long)gr * N;
            if (colb >= 0 && colb + 7 < N) {
                a = *(const float4*)(row + colb);
                b = *(const float4*)(row + colb + 4);
            } else {
                float v[8];
                #pragma unroll
                for (int j = 0; j < 8; ++j)
                    v[j] = (colb + j >= 0 && colb + j < N) ? row[colb + j] : 0.f;
                a = make_float4(v[0], v[1], v[2], v[3]);
                b = make_float4(v[4], v[5], v[6], v[7]);
            }
        }
        pA[k] = a; pB[k] = b;
    }

    float* wrTop = &bnd[(NB + g) * PS + 8 * c];
    float* wrBot = &bnd[g * PS + 8 * c];
    const float* rdUp = &bnd[((g > 0) ? (g - 1) : 0) * PS + 8 * c];        // bbot[g-1]
    const float* rdDn = &bnd[(NB + ((g < NB - 1) ? (g + 1) : g)) * PS + 8 * c]; // btop[g+1]

    for (int s = 0; s < SWP; ++s) {
        // publish old boundary rows
        *(float4*)(wrTop)     = pA[0];
        *(float4*)(wrTop + 4) = pB[0];
        *(float4*)(wrBot)     = pA[3];
        *(float4*)(wrBot + 4) = pB[3];
        __syncthreads();
        float4 upA = make_float4(0.f, 0.f, 0.f, 0.f), upB = upA;
        float4 dnA = upA, dnB = upA;
        if (g > 0)      { upA = *(const float4*)rdUp; upB = *(const float4*)(rdUp + 4); }
        if (g < NB - 1) { dnA = *(const float4*)rdDn; dnB = *(const float4*)(rdDn + 4); }
        __syncthreads();   // reads done; next sweep may overwrite bnd

        float4 poA = upA, poB = upB;  // old row above current row
        #pragma unroll
        for (int k = 0; k < 4; ++k) {
            float4 cA = pA[k], cB = pB[k];
            float4 dA = (k < 3) ? pA[k + 1] : dnA;   // still old values
            float4 dB = (k < 3) ? pB[k + 1] : dnB;
            float lf = __shfl_up(cB.w, 1);
            float rg = __shfl_down(cA.x, 1);
            lf = (c == 0)  ? 0.f : lf;
            rg = (c == 15) ? 0.f : rg;
            float r = rm[k];
            float4 nA, nB;
            nA.x = (poA.x + dA.x + lf   + cA.y) * (f[0] * r);
            nA.y = (poA.y + dA.y + cA.x + cA.z) * (f[1] * r);
            nA.z = (poA.z + dA.z + cA.y + cA.w) * (f[2] * r);
            nA.w = (poA.w + dA.w + cA.z + cB.x) * (f[3] * r);
            nB.x = (poB.x + dB.x + cA.w + cB.y) * (f[4] * r);
            nB.y = (poB.y + dB.y + cB.x + cB.z) * (f[5] * r);
            nB.z = (poB.z + dB.z + cB.y + cB.w) * (f[6] * r);
            nB.w = (poB.w + dB.w + cB.z + rg  ) * (f[7] * r);
            pA[k] = nA; pB[k] = nB;
            poA = cA; poB = cB;
        }
    }

    // ---- store valid interior: window rows 10..53, cols 10..117 ----
    #pragma unroll
    for (int k = 0; k < 4; ++k) {
        int w = 4 * g + k;
        if (w >= HALO && w < WY - HALO) {
            float* orow = out + (long)(gy0 + w) * N;
            if (c >= 2 && c <= 13) {
                *(float4*)(orow + colb)     = pA[k];
                *(float4*)(orow + colb + 4) = pB[k];
            } else if (c == 1) {          // cols 8..15 -> keep 10..15
                float2 v; v.x = pA[k].z; v.y = pA[k].w;
                *(float2*)(orow + gx0 + 10) = v;
                *(float4*)(orow + gx0 + 12) = pB[k];
            } else if (c == 14) {         // cols 112..119 -> keep 112..117
                *(float4*)(orow + colb) = pA[k];
                float2 v; v.x = pB[k].x; v.y = pB[k].y;
                *(float2*)(orow + gx0 + 116) = v;
            }
        }
    }
}

extern "C" void kernel_launch(void* const* d_in, const int* in_sizes, int n_in,
                              void* d_out, int out_size, void* d_ws, size_t ws_size,
                              hipStream_t stream) {
    const float* X = (const float*)d_in[0];
    const float* Y = (const float*)d_in[1];

    float* a = (float*)d_out;   // ping
    float* b = (float*)d_ws;    // pong (16 MiB of workspace)

    jm_init<<<(N * N / 4) / 256, 256, 0, stream>>>((const float4*)X, (const float4*)Y,
                                                   (float4*)a);

    // 100 sweeps = 10 launches x 10 fused sweeps; even -> final lands in d_out
    for (int it = 0; it < 10; ++it) {
        jm_sweep<<<NTX * NTY, NTHR, 0, stream>>>(a, b);
        float* tp = a; a = b; b = tp;
    }
}

// Round 11
// 254.730 us; speedup vs baseline: 1.3841x; 1.0344x over previous
//
#include <hip/hip_runtime.h>

#define N      2048
#define HALO   10            // sweeps fused per launch
#define SWP    10
#define WX     128           // window width (16 threads x 8 cols)
#define WY     64            // window rows  (16 bands x 4 rows)
#define TX     108           // output tile width
#define TY     44            // output tile height
#define NTX    19            // last tile clamped; overlap writes identical values
#define NTY    47
#define NTHR   256
#define NB     16            // bands of 4 rows
#define PS     132           // LDS boundary row stride (words)
#define BUFW   (2*NB*PS)     // one slab: 4224 words; two slabs = 33.8 KB

// ---- init: x = exp(-50*((X-0.5)^2 + (Y-0.5)^2)) ----
__global__ __launch_bounds__(256) void jm_init(const float4* __restrict__ X,
                                               const float4* __restrict__ Y,
                                               float4* __restrict__ out) {
    int t = blockIdx.x * 256 + threadIdx.x;
    float4 x = X[t];
    float4 y = Y[t];
    float4 r;
    r.x = expf(-50.f * ((x.x - 0.5f) * (x.x - 0.5f) + (y.x - 0.5f) * (y.x - 0.5f)));
    r.y = expf(-50.f * ((x.y - 0.5f) * (x.y - 0.5f) + (y.y - 0.5f) * (y.y - 0.5f)));
    r.z = expf(-50.f * ((x.z - 0.5f) * (x.z - 0.5f) + (y.z - 0.5f) * (y.z - 0.5f)));
    r.w = expf(-50.f * ((x.w - 0.5f) * (x.w - 0.5f) + (y.w - 0.5f) * (y.w - 0.5f)));
    out[t] = r;
}

// Register-resident fused sweeps: each thread owns a 4x8 patch in VGPRs.
// LDS ping-pong slabs hold only band-boundary rows -> 1 barrier/sweep.
// (Slab s&1 is rewritten only in sweep s+2, behind the collective barrier
// of sweep s+1, so no read/write race.) lf/rg neighbors via wave shuffles.
// Contamination advances 1 cell/sweep; stored cells sit at window distance
// >= HALO -> exact after HALO sweeps.
__global__ __launch_bounds__(NTHR) void jm_sweep(const float* __restrict__ in,
                                                 float* __restrict__ out) {
    __shared__ float bnd[2 * BUFW];      // per slab: [0..15]=bbot(g), [16..31]=btop(g)
    const int bx = blockIdx.x % NTX;
    const int by = blockIdx.x / NTX;
    const int ox = (bx < NTX - 1) ? bx * TX : (N - TX);
    const int oy = (by < NTY - 1) ? by * TY : (N - TY);
    const int gx0 = ox - HALO, gy0 = oy - HALO;
    const int t = threadIdx.x;
    const int c = t & 15;                // column chunk (8 cols)
    const int g = t >> 4;                // band
    const int colb = gx0 + 8 * c;        // global col of patch col 0

    // column mask factors (0.25 interior, 0 on/outside boundary) and row masks
    float f[8];
    #pragma unroll
    for (int j = 0; j < 8; ++j)
        f[j] = (colb + j >= 1 && colb + j <= N - 2) ? 0.25f : 0.f;
    float rm[4];
    #pragma unroll
    for (int k = 0; k < 4; ++k) {
        int gr = gy0 + 4 * g + k;
        rm[k] = (gr >= 1 && gr <= N - 2) ? 1.f : 0.f;
    }

    // ---- load 4x8 patch (out-of-domain -> 0) ----
    float4 pA[4], pB[4];
    #pragma unroll
    for (int k = 0; k < 4; ++k) {
        int gr = gy0 + 4 * g + k;
        float4 a = make_float4(0.f, 0.f, 0.f, 0.f);
        float4 b = make_float4(0.f, 0.f, 0.f, 0.f);
        if (gr >= 0 && gr < N) {
            const float* row = in + (long)gr * N;
            if (colb >= 0 && colb + 7 < N) {
                a = *(const float4*)(row + colb);
                b = *(const float4*)(row + colb + 4);
            } else {
                float v[8];
                #pragma unroll
                for (int j = 0; j < 8; ++j)
                    v[j] = (colb + j >= 0 && colb + j < N) ? row[colb + j] : 0.f;
                a = make_float4(v[0], v[1], v[2], v[3]);
                b = make_float4(v[4], v[5], v[6], v[7]);
            }
        }
        pA[k] = a; pB[k] = b;
    }

    const int co = 8 * c;
    const int wT = (NB + g) * PS + co;          // my top row slot
    const int wB = g * PS + co;                 // my bottom row slot
    const int rU = ((g > 0) ? (g - 1) : 0) * PS + co;              // bbot[g-1]
    const int rD = (NB + ((g < NB - 1) ? (g + 1) : g)) * PS + co;  // btop[g+1]

    for (int s = 0; s < SWP; ++s) {
        float* buf = bnd + (s & 1) * BUFW;
        // publish old boundary rows
        *(float4*)(buf + wT)     = pA[0];
        *(float4*)(buf + wT + 4) = pB[0];
        *(float4*)(buf + wB)     = pA[3];
        *(float4*)(buf + wB + 4) = pB[3];
        __syncthreads();                        // only barrier this sweep
        float4 upA = make_float4(0.f, 0.f, 0.f, 0.f), upB = upA;
        float4 dnA = upA, dnB = upA;
        if (g > 0)      { upA = *(const float4*)(buf + rU); upB = *(const float4*)(buf + rU + 4); }
        if (g < NB - 1) { dnA = *(const float4*)(buf + rD); dnB = *(const float4*)(buf + rD + 4); }

        float4 poA = upA, poB = upB;  // old row above current row
        #pragma unroll
        for (int k = 0; k < 4; ++k) {
            float4 cA = pA[k], cB = pB[k];
            float4 dA = (k < 3) ? pA[k + 1] : dnA;   // still old values
            float4 dB = (k < 3) ? pB[k + 1] : dnB;
            float lf = __shfl_up(cB.w, 1);
            float rg = __shfl_down(cA.x, 1);
            lf = (c == 0)  ? 0.f : lf;
            rg = (c == 15) ? 0.f : rg;
            float r = rm[k];
            float4 nA, nB;
            nA.x = (poA.x + dA.x + lf   + cA.y) * (f[0] * r);
            nA.y = (poA.y + dA.y + cA.x + cA.z) * (f[1] * r);
            nA.z = (poA.z + dA.z + cA.y + cA.w) * (f[2] * r);
            nA.w = (poA.w + dA.w + cA.z + cB.x) * (f[3] * r);
            nB.x = (poB.x + dB.x + cA.w + cB.y) * (f[4] * r);
            nB.y = (poB.y + dB.y + cB.x + cB.z) * (f[5] * r);
            nB.z = (poB.z + dB.z + cB.y + cB.w) * (f[6] * r);
            nB.w = (poB.w + dB.w + cB.z + rg  ) * (f[7] * r);
            pA[k] = nA; pB[k] = nB;
            poA = cA; poB = cB;
        }
    }

    // ---- store valid interior: window rows 10..53, cols 10..117 ----
    #pragma unroll
    for (int k = 0; k < 4; ++k) {
        int w = 4 * g + k;
        if (w >= HALO && w < WY - HALO) {
            float* orow = out + (long)(gy0 + w) * N;
            if (c >= 2 && c <= 13) {
                *(float4*)(orow + colb)     = pA[k];
                *(float4*)(orow + colb + 4) = pB[k];
            } else if (c == 1) {          // cols 8..15 -> keep 10..15
                float2 v; v.x = pA[k].z; v.y = pA[k].w;
                *(float2*)(orow + gx0 + 10) = v;
                *(float4*)(orow + gx0 + 12) = pB[k];
            } else if (c == 14) {         // cols 112..119 -> keep 112..117
                *(float4*)(orow + colb) = pA[k];
                float2 v; v.x = pB[k].x; v.y = pB[k].y;
                *(float2*)(orow + gx0 + 116) = v;
            }
        }
    }
}

extern "C" void kernel_launch(void* const* d_in, const int* in_sizes, int n_in,
                              void* d_out, int out_size, void* d_ws, size_t ws_size,
                              hipStream_t stream) {
    const float* X = (const float*)d_in[0];
    const float* Y = (const float*)d_in[1];

    float* a = (float*)d_out;   // ping
    float* b = (float*)d_ws;    // pong (16 MiB of workspace)

    jm_init<<<(N * N / 4) / 256, 256, 0, stream>>>((const float4*)X, (const float4*)Y,
                                                   (float4*)a);

    // 100 sweeps = 10 launches x 10 fused sweeps; even -> final lands in d_out
    for (int it = 0; it < 10; ++it) {
        jm_sweep<<<NTX * NTY, NTHR, 0, stream>>>(a, b);
        float* tp = a; a = b; b = tp;
    }
}

// Round 16
// 254.230 us; speedup vs baseline: 1.3868x; 1.0020x over previous
//
#include <hip/hip_runtime.h>

#define N      2048
#define HALO   10            // sweeps fused per launch
#define SWP    10
#define WX     128           // window width (16 threads x 8 cols)
#define WY     64            // window rows  (16 bands x 4 rows)
#define TX     108           // output tile width
#define TY     44            // output tile height
#define NTX    19            // last tile clamped; overlap writes identical values
#define NTY    47
#define NTHR   256
#define NB     16            // bands of 4 rows
#define PS     132           // LDS boundary row stride (words)
#define BUFW   (2*NB*PS)     // one slab: 4224 words; two slabs = 33.8 KB

__device__ __forceinline__ float bump(float xv, float yv) {
    float dx = xv - 0.5f, dy = yv - 0.5f;
    return expf(-50.f * (dx * dx + dy * dy));
}

// Shared sweep machinery (macro-free, repeated verbatim in both kernels to
// avoid cross-instantiation regalloc coupling — see R8/R9 regression).
// Register-resident fused sweeps: each thread owns a 4x8 patch in VGPRs.
// LDS ping-pong slabs hold only band-boundary rows -> 1 barrier/sweep.
// Contamination advances 1 cell/sweep; stored cells sit at window distance
// >= HALO -> exact after HALO sweeps.

// ---- first launch: init fused (patch = exp bump from X,Y), then 10 sweeps ----
__global__ __launch_bounds__(NTHR) void jm_sweep0(const float* __restrict__ X,
                                                  const float* __restrict__ Y,
                                                  float* __restrict__ out) {
    __shared__ float bnd[2 * BUFW];
    const int bx = blockIdx.x % NTX;
    const int by = blockIdx.x / NTX;
    const int ox = (bx < NTX - 1) ? bx * TX : (N - TX);
    const int oy = (by < NTY - 1) ? by * TY : (N - TY);
    const int gx0 = ox - HALO, gy0 = oy - HALO;
    const int t = threadIdx.x;
    const int c = t & 15;
    const int g = t >> 4;
    const int colb = gx0 + 8 * c;

    float f[8];
    #pragma unroll
    for (int j = 0; j < 8; ++j)
        f[j] = (colb + j >= 1 && colb + j <= N - 2) ? 0.25f : 0.f;
    float rm[4];
    #pragma unroll
    for (int k = 0; k < 4; ++k) {
        int gr = gy0 + 4 * g + k;
        rm[k] = (gr >= 1 && gr <= N - 2) ? 1.f : 0.f;
    }

    // ---- init patch directly from X,Y (out-of-domain -> 0) ----
    float4 pA[4], pB[4];
    #pragma unroll
    for (int k = 0; k < 4; ++k) {
        int gr = gy0 + 4 * g + k;
        float4 a = make_float4(0.f, 0.f, 0.f, 0.f), b = a;
        if (gr >= 0 && gr < N) {
            const float* xr = X + (long)gr * N;
            const float* yr = Y + (long)gr * N;
            if (colb >= 0 && colb + 7 < N) {
                float4 x0 = *(const float4*)(xr + colb);
                float4 x1 = *(const float4*)(xr + colb + 4);
                float4 y0 = *(const float4*)(yr + colb);
                float4 y1 = *(const float4*)(yr + colb + 4);
                a.x = bump(x0.x, y0.x); a.y = bump(x0.y, y0.y);
                a.z = bump(x0.z, y0.z); a.w = bump(x0.w, y0.w);
                b.x = bump(x1.x, y1.x); b.y = bump(x1.y, y1.y);
                b.z = bump(x1.z, y1.z); b.w = bump(x1.w, y1.w);
            } else {
                float v[8];
                #pragma unroll
                for (int j = 0; j < 8; ++j) {
                    int gc = colb + j;
                    v[j] = (gc >= 0 && gc < N) ? bump(xr[gc], yr[gc]) : 0.f;
                }
                a = make_float4(v[0], v[1], v[2], v[3]);
                b = make_float4(v[4], v[5], v[6], v[7]);
            }
        }
        pA[k] = a; pB[k] = b;
    }

    const int co = 8 * c;
    const int wT = (NB + g) * PS + co;
    const int wB = g * PS + co;
    const int rU = ((g > 0) ? (g - 1) : 0) * PS + co;
    const int rD = (NB + ((g < NB - 1) ? (g + 1) : g)) * PS + co;

    for (int s = 0; s < SWP; ++s) {
        float* buf = bnd + (s & 1) * BUFW;
        *(float4*)(buf + wT)     = pA[0];
        *(float4*)(buf + wT + 4) = pB[0];
        *(float4*)(buf + wB)     = pA[3];
        *(float4*)(buf + wB + 4) = pB[3];
        __syncthreads();
        float4 upA = make_float4(0.f, 0.f, 0.f, 0.f), upB = upA;
        float4 dnA = upA, dnB = upA;
        if (g > 0)      { upA = *(const float4*)(buf + rU); upB = *(const float4*)(buf + rU + 4); }
        if (g < NB - 1) { dnA = *(const float4*)(buf + rD); dnB = *(const float4*)(buf + rD + 4); }

        float4 poA = upA, poB = upB;
        #pragma unroll
        for (int k = 0; k < 4; ++k) {
            float4 cA = pA[k], cB = pB[k];
            float4 dA = (k < 3) ? pA[k + 1] : dnA;
            float4 dB = (k < 3) ? pB[k + 1] : dnB;
            float lf = __shfl_up(cB.w, 1);
            float rg = __shfl_down(cA.x, 1);
            lf = (c == 0)  ? 0.f : lf;
            rg = (c == 15) ? 0.f : rg;
            float r = rm[k];
            float4 nA, nB;
            nA.x = (poA.x + dA.x + lf   + cA.y) * (f[0] * r);
            nA.y = (poA.y + dA.y + cA.x + cA.z) * (f[1] * r);
            nA.z = (poA.z + dA.z + cA.y + cA.w) * (f[2] * r);
            nA.w = (poA.w + dA.w + cA.z + cB.x) * (f[3] * r);
            nB.x = (poB.x + dB.x + cA.w + cB.y) * (f[4] * r);
            nB.y = (poB.y + dB.y + cB.x + cB.z) * (f[5] * r);
            nB.z = (poB.z + dB.z + cB.y + cB.w) * (f[6] * r);
            nB.w = (poB.w + dB.w + cB.z + rg  ) * (f[7] * r);
            pA[k] = nA; pB[k] = nB;
            poA = cA; poB = cB;
        }
    }

    #pragma unroll
    for (int k = 0; k < 4; ++k) {
        int w = 4 * g + k;
        if (w >= HALO && w < WY - HALO) {
            float* orow = out + (long)(gy0 + w) * N;
            if (c >= 2 && c <= 13) {
                *(float4*)(orow + colb)     = pA[k];
                *(float4*)(orow + colb + 4) = pB[k];
            } else if (c == 1) {
                float2 v; v.x = pA[k].z; v.y = pA[k].w;
                *(float2*)(orow + gx0 + 10) = v;
                *(float4*)(orow + gx0 + 12) = pB[k];
            } else if (c == 14) {
                *(float4*)(orow + colb) = pA[k];
                float2 v; v.x = pB[k].x; v.y = pB[k].y;
                *(float2*)(orow + gx0 + 116) = v;
            }
        }
    }
}

// ---- steady-state launch: load field window, 10 sweeps (R11 champion) ----
__global__ __launch_bounds__(NTHR) void jm_sweep(const float* __restrict__ in,
                                                 float* __restrict__ out) {
    __shared__ float bnd[2 * BUFW];
    const int bx = blockIdx.x % NTX;
    const int by = blockIdx.x / NTX;
    const int ox = (bx < NTX - 1) ? bx * TX : (N - TX);
    const int oy = (by < NTY - 1) ? by * TY : (N - TY);
    const int gx0 = ox - HALO, gy0 = oy - HALO;
    const int t = threadIdx.x;
    const int c = t & 15;
    const int g = t >> 4;
    const int colb = gx0 + 8 * c;

    float f[8];
    #pragma unroll
    for (int j = 0; j < 8; ++j)
        f[j] = (colb + j >= 1 && colb + j <= N - 2) ? 0.25f : 0.f;
    float rm[4];
    #pragma unroll
    for (int k = 0; k < 4; ++k) {
        int gr = gy0 + 4 * g + k;
        rm[k] = (gr >= 1 && gr <= N - 2) ? 1.f : 0.f;
    }

    float4 pA[4], pB[4];
    #pragma unroll
    for (int k = 0; k < 4; ++k) {
        int gr = gy0 + 4 * g + k;
        float4 a = make_float4(0.f, 0.f, 0.f, 0.f), b = a;
        if (gr >= 0 && gr < N) {
            const float* row = in + (long)gr * N;
            if (colb >= 0 && colb + 7 < N) {
                a = *(const float4*)(row + colb);
                b = *(const float4*)(row + colb + 4);
            } else {
                float v[8];
                #pragma unroll
                for (int j = 0; j < 8; ++j)
                    v[j] = (colb + j >= 0 && colb + j < N) ? row[colb + j] : 0.f;
                a = make_float4(v[0], v[1], v[2], v[3]);
                b = make_float4(v[4], v[5], v[6], v[7]);
            }
        }
        pA[k] = a; pB[k] = b;
    }

    const int co = 8 * c;
    const int wT = (NB + g) * PS + co;
    const int wB = g * PS + co;
    const int rU = ((g > 0) ? (g - 1) : 0) * PS + co;
    const int rD = (NB + ((g < NB - 1) ? (g + 1) : g)) * PS + co;

    for (int s = 0; s < SWP; ++s) {
        float* buf = bnd + (s & 1) * BUFW;
        *(float4*)(buf + wT)     = pA[0];
        *(float4*)(buf + wT + 4) = pB[0];
        *(float4*)(buf + wB)     = pA[3];
        *(float4*)(buf + wB + 4) = pB[3];
        __syncthreads();
        float4 upA = make_float4(0.f, 0.f, 0.f, 0.f), upB = upA;
        float4 dnA = upA, dnB = upA;
        if (g > 0)      { upA = *(const float4*)(buf + rU); upB = *(const float4*)(buf + rU + 4); }
        if (g < NB - 1) { dnA = *(const float4*)(buf + rD); dnB = *(const float4*)(buf + rD + 4); }

        float4 poA = upA, poB = upB;
        #pragma unroll
        for (int k = 0; k < 4; ++k) {
            float4 cA = pA[k], cB = pB[k];
            float4 dA = (k < 3) ? pA[k + 1] : dnA;
            float4 dB = (k < 3) ? pB[k + 1] : dnB;
            float lf = __shfl_up(cB.w, 1);
            float rg = __shfl_down(cA.x, 1);
            lf = (c == 0)  ? 0.f : lf;
            rg = (c == 15) ? 0.f : rg;
            float r = rm[k];
            float4 nA, nB;
            nA.x = (poA.x + dA.x + lf   + cA.y) * (f[0] * r);
            nA.y = (poA.y + dA.y + cA.x + cA.z) * (f[1] * r);
            nA.z = (poA.z + dA.z + cA.y + cA.w) * (f[2] * r);
            nA.w = (poA.w + dA.w + cA.z + cB.x) * (f[3] * r);
            nB.x = (poB.x + dB.x + cA.w + cB.y) * (f[4] * r);
            nB.y = (poB.y + dB.y + cB.x + cB.z) * (f[5] * r);
            nB.z = (poB.z + dB.z + cB.y + cB.w) * (f[6] * r);
            nB.w = (poB.w + dB.w + cB.z + rg  ) * (f[7] * r);
            pA[k] = nA; pB[k] = nB;
            poA = cA; poB = cB;
        }
    }

    #pragma unroll
    for (int k = 0; k < 4; ++k) {
        int w = 4 * g + k;
        if (w >= HALO && w < WY - HALO) {
            float* orow = out + (long)(gy0 + w) * N;
            if (c >= 2 && c <= 13) {
                *(float4*)(orow + colb)     = pA[k];
                *(float4*)(orow + colb + 4) = pB[k];
            } else if (c == 1) {
                float2 v; v.x = pA[k].z; v.y = pA[k].w;
                *(float2*)(orow + gx0 + 10) = v;
                *(float4*)(orow + gx0 + 12) = pB[k];
            } else if (c == 14) {
                *(float4*)(orow + colb) = pA[k];
                float2 v; v.x = pB[k].x; v.y = pB[k].y;
                *(float2*)(orow + gx0 + 116) = v;
            }
        }
    }
}

extern "C" void kernel_launch(void* const* d_in, const int* in_sizes, int n_in,
                              void* d_out, int out_size, void* d_ws, size_t ws_size,
                              hipStream_t stream) {
    const float* X = (const float*)d_in[0];
    const float* Y = (const float*)d_in[1];
    float* out = (float*)d_out;
    float* ws  = (float*)d_ws;

    // launch 1: init fused + sweeps 1..10 -> ws
    jm_sweep0<<<NTX * NTY, NTHR, 0, stream>>>(X, Y, ws);

    // launches 2..10: sweeps 11..100, ping-pong; 9 launches (odd) -> ends in out
    float* a = ws;
    float* b = out;
    for (int it = 0; it < 9; ++it) {
        jm_sweep<<<NTX * NTY, NTHR, 0, stream>>>(a, b);
        float* tp = a; a = b; b = tp;
    }
}

// Round 18
// 231.492 us; speedup vs baseline: 1.5231x; 1.0982x over previous
//
#include <hip/hip_runtime.h>

#define N      2048
#define HALO   10            // sweeps fused per launch
#define SWP    10
#define WX     128           // window width (16 threads x 8 cols)
#define WY     64            // window rows  (16 bands x 4 rows)
#define TX     108           // output tile width
#define TY     44            // output tile height
#define NTX    19            // last tile clamped; overlap writes identical values
#define NTY    47
#define NTHR   256
#define NB     16            // bands of 4 rows
#define PS     132           // LDS boundary row stride (words)
#define BUFW   (2*NB*PS)     // one slab: 4224 words; two slabs = 33.8 KB
// XCD swizzle (bijective, m204 form): NWG=893, q=111, r=5 -> XCD 0..4 own 112
// consecutive tile-ids, XCD 5..7 own 111. Same mapping every launch => each
// XCD re-reads its own previous writes from its own L2.
#define NWGQ   111
#define NWGR   5

__device__ __forceinline__ float bump(float xv, float yv) {
    float dx = xv - 0.5f, dy = yv - 0.5f;
    return expf(-50.f * (dx * dx + dy * dy));
}

__device__ __forceinline__ int swz_wgid(int bid) {
    int xcd = bid & 7;
    int j   = bid >> 3;
    int start = (xcd < NWGR) ? xcd * (NWGQ + 1)
                             : NWGR * (NWGQ + 1) + (xcd - NWGR) * NWGQ;
    return start + j;
}

// Shared sweep machinery (repeated verbatim in both kernels to avoid
// cross-instantiation regalloc coupling — see R8/R9 regression).
// Register-resident fused sweeps: each thread owns a 4x8 patch in VGPRs.
// LDS ping-pong slabs hold only band-boundary rows -> 1 barrier/sweep.
// Contamination advances 1 cell/sweep; stored cells sit at window distance
// >= HALO -> exact after HALO sweeps.

// ---- first launch: init fused (patch = exp bump from X,Y), then 10 sweeps ----
__global__ __launch_bounds__(NTHR) void jm_sweep0(const float* __restrict__ X,
                                                  const float* __restrict__ Y,
                                                  float* __restrict__ out) {
    __shared__ float bnd[2 * BUFW];
    const int wgid = swz_wgid(blockIdx.x);
    const int bx = wgid % NTX;
    const int by = wgid / NTX;
    const int ox = (bx < NTX - 1) ? bx * TX : (N - TX);
    const int oy = (by < NTY - 1) ? by * TY : (N - TY);
    const int gx0 = ox - HALO, gy0 = oy - HALO;
    const int t = threadIdx.x;
    const int c = t & 15;
    const int g = t >> 4;
    const int colb = gx0 + 8 * c;

    float f[8];
    #pragma unroll
    for (int j = 0; j < 8; ++j)
        f[j] = (colb + j >= 1 && colb + j <= N - 2) ? 0.25f : 0.f;
    float rm[4];
    #pragma unroll
    for (int k = 0; k < 4; ++k) {
        int gr = gy0 + 4 * g + k;
        rm[k] = (gr >= 1 && gr <= N - 2) ? 1.f : 0.f;
    }

    // ---- init patch directly from X,Y (out-of-domain -> 0) ----
    float4 pA[4], pB[4];
    #pragma unroll
    for (int k = 0; k < 4; ++k) {
        int gr = gy0 + 4 * g + k;
        float4 a = make_float4(0.f, 0.f, 0.f, 0.f), b = a;
        if (gr >= 0 && gr < N) {
            const float* xr = X + (long)gr * N;
            const float* yr = Y + (long)gr * N;
            if (colb >= 0 && colb + 7 < N) {
                float4 x0 = *(const float4*)(xr + colb);
                float4 x1 = *(const float4*)(xr + colb + 4);
                float4 y0 = *(const float4*)(yr + colb);
                float4 y1 = *(const float4*)(yr + colb + 4);
                a.x = bump(x0.x, y0.x); a.y = bump(x0.y, y0.y);
                a.z = bump(x0.z, y0.z); a.w = bump(x0.w, y0.w);
                b.x = bump(x1.x, y1.x); b.y = bump(x1.y, y1.y);
                b.z = bump(x1.z, y1.z); b.w = bump(x1.w, y1.w);
            } else {
                float v[8];
                #pragma unroll
                for (int j = 0; j < 8; ++j) {
                    int gc = colb + j;
                    v[j] = (gc >= 0 && gc < N) ? bump(xr[gc], yr[gc]) : 0.f;
                }
                a = make_float4(v[0], v[1], v[2], v[3]);
                b = make_float4(v[4], v[5], v[6], v[7]);
            }
        }
        pA[k] = a; pB[k] = b;
    }

    const int co = 8 * c;
    const int wT = (NB + g) * PS + co;
    const int wB = g * PS + co;
    const int rU = ((g > 0) ? (g - 1) : 0) * PS + co;
    const int rD = (NB + ((g < NB - 1) ? (g + 1) : g)) * PS + co;

    for (int s = 0; s < SWP; ++s) {
        float* buf = bnd + (s & 1) * BUFW;
        *(float4*)(buf + wT)     = pA[0];
        *(float4*)(buf + wT + 4) = pB[0];
        *(float4*)(buf + wB)     = pA[3];
        *(float4*)(buf + wB + 4) = pB[3];
        __syncthreads();
        float4 upA = make_float4(0.f, 0.f, 0.f, 0.f), upB = upA;
        float4 dnA = upA, dnB = upA;
        if (g > 0)      { upA = *(const float4*)(buf + rU); upB = *(const float4*)(buf + rU + 4); }
        if (g < NB - 1) { dnA = *(const float4*)(buf + rD); dnB = *(const float4*)(buf + rD + 4); }

        float4 poA = upA, poB = upB;
        #pragma unroll
        for (int k = 0; k < 4; ++k) {
            float4 cA = pA[k], cB = pB[k];
            float4 dA = (k < 3) ? pA[k + 1] : dnA;
            float4 dB = (k < 3) ? pB[k + 1] : dnB;
            float lf = __shfl_up(cB.w, 1);
            float rg = __shfl_down(cA.x, 1);
            lf = (c == 0)  ? 0.f : lf;
            rg = (c == 15) ? 0.f : rg;
            float r = rm[k];
            float4 nA, nB;
            nA.x = (poA.x + dA.x + lf   + cA.y) * (f[0] * r);
            nA.y = (poA.y + dA.y + cA.x + cA.z) * (f[1] * r);
            nA.z = (poA.z + dA.z + cA.y + cA.w) * (f[2] * r);
            nA.w = (poA.w + dA.w + cA.z + cB.x) * (f[3] * r);
            nB.x = (poB.x + dB.x + cA.w + cB.y) * (f[4] * r);
            nB.y = (poB.y + dB.y + cB.x + cB.z) * (f[5] * r);
            nB.z = (poB.z + dB.z + cB.y + cB.w) * (f[6] * r);
            nB.w = (poB.w + dB.w + cB.z + rg  ) * (f[7] * r);
            pA[k] = nA; pB[k] = nB;
            poA = cA; poB = cB;
        }
    }

    #pragma unroll
    for (int k = 0; k < 4; ++k) {
        int w = 4 * g + k;
        if (w >= HALO && w < WY - HALO) {
            float* orow = out + (long)(gy0 + w) * N;
            if (c >= 2 && c <= 13) {
                *(float4*)(orow + colb)     = pA[k];
                *(float4*)(orow + colb + 4) = pB[k];
            } else if (c == 1) {
                float2 v; v.x = pA[k].z; v.y = pA[k].w;
                *(float2*)(orow + gx0 + 10) = v;
                *(float4*)(orow + gx0 + 12) = pB[k];
            } else if (c == 14) {
                *(float4*)(orow + colb) = pA[k];
                float2 v; v.x = pB[k].x; v.y = pB[k].y;
                *(float2*)(orow + gx0 + 116) = v;
            }
        }
    }
}

// ---- steady-state launch: load field window, 10 sweeps (R11 champion) ----
__global__ __launch_bounds__(NTHR) void jm_sweep(const float* __restrict__ in,
                                                 float* __restrict__ out) {
    __shared__ float bnd[2 * BUFW];
    const int wgid = swz_wgid(blockIdx.x);
    const int bx = wgid % NTX;
    const int by = wgid / NTX;
    const int ox = (bx < NTX - 1) ? bx * TX : (N - TX);
    const int oy = (by < NTY - 1) ? by * TY : (N - TY);
    const int gx0 = ox - HALO, gy0 = oy - HALO;
    const int t = threadIdx.x;
    const int c = t & 15;
    const int g = t >> 4;
    const int colb = gx0 + 8 * c;

    float f[8];
    #pragma unroll
    for (int j = 0; j < 8; ++j)
        f[j] = (colb + j >= 1 && colb + j <= N - 2) ? 0.25f : 0.f;
    float rm[4];
    #pragma unroll
    for (int k = 0; k < 4; ++k) {
        int gr = gy0 + 4 * g + k;
        rm[k] = (gr >= 1 && gr <= N - 2) ? 1.f : 0.f;
    }

    float4 pA[4], pB[4];
    #pragma unroll
    for (int k = 0; k < 4; ++k) {
        int gr = gy0 + 4 * g + k;
        float4 a = make_float4(0.f, 0.f, 0.f, 0.f), b = a;
        if (gr >= 0 && gr < N) {
            const float* row = in + (long)gr * N;
            if (colb >= 0 && colb + 7 < N) {
                a = *(const float4*)(row + colb);
                b = *(const float4*)(row + colb + 4);
            } else {
                float v[8];
                #pragma unroll
                for (int j = 0; j < 8; ++j)
                    v[j] = (colb + j >= 0 && colb + j < N) ? row[colb + j] : 0.f;
                a = make_float4(v[0], v[1], v[2], v[3]);
                b = make_float4(v[4], v[5], v[6], v[7]);
            }
        }
        pA[k] = a; pB[k] = b;
    }

    const int co = 8 * c;
    const int wT = (NB + g) * PS + co;
    const int wB = g * PS + co;
    const int rU = ((g > 0) ? (g - 1) : 0) * PS + co;
    const int rD = (NB + ((g < NB - 1) ? (g + 1) : g)) * PS + co;

    for (int s = 0; s < SWP; ++s) {
        float* buf = bnd + (s & 1) * BUFW;
        *(float4*)(buf + wT)     = pA[0];
        *(float4*)(buf + wT + 4) = pB[0];
        *(float4*)(buf + wB)     = pA[3];
        *(float4*)(buf + wB + 4) = pB[3];
        __syncthreads();
        float4 upA = make_float4(0.f, 0.f, 0.f, 0.f), upB = upA;
        float4 dnA = upA, dnB = upA;
        if (g > 0)      { upA = *(const float4*)(buf + rU); upB = *(const float4*)(buf + rU + 4); }
        if (g < NB - 1) { dnA = *(const float4*)(buf + rD); dnB = *(const float4*)(buf + rD + 4); }

        float4 poA = upA, poB = upB;
        #pragma unroll
        for (int k = 0; k < 4; ++k) {
            float4 cA = pA[k], cB = pB[k];
            float4 dA = (k < 3) ? pA[k + 1] : dnA;
            float4 dB = (k < 3) ? pB[k + 1] : dnB;
            float lf = __shfl_up(cB.w, 1);
            float rg = __shfl_down(cA.x, 1);
            lf = (c == 0)  ? 0.f : lf;
            rg = (c == 15) ? 0.f : rg;
            float r = rm[k];
            float4 nA, nB;
            nA.x = (poA.x + dA.x + lf   + cA.y) * (f[0] * r);
            nA.y = (poA.y + dA.y + cA.x + cA.z) * (f[1] * r);
            nA.z = (poA.z + dA.z + cA.y + cA.w) * (f[2] * r);
            nA.w = (poA.w + dA.w + cA.z + cB.x) * (f[3] * r);
            nB.x = (poB.x + dB.x + cA.w + cB.y) * (f[4] * r);
            nB.y = (poB.y + dB.y + cB.x + cB.z) * (f[5] * r);
            nB.z = (poB.z + dB.z + cB.y + cB.w) * (f[6] * r);
            nB.w = (poB.w + dB.w + cB.z + rg  ) * (f[7] * r);
            pA[k] = nA; pB[k] = nB;
            poA = cA; poB = cB;
        }
    }

    #pragma unroll
    for (int k = 0; k < 4; ++k) {
        int w = 4 * g + k;
        if (w >= HALO && w < WY - HALO) {
            float* orow = out + (long)(gy0 + w) * N;
            if (c >= 2 && c <= 13) {
                *(float4*)(orow + colb)     = pA[k];
                *(float4*)(orow + colb + 4) = pB[k];
            } else if (c == 1) {
                float2 v; v.x = pA[k].z; v.y = pA[k].w;
                *(float2*)(orow + gx0 + 10) = v;
                *(float4*)(orow + gx0 + 12) = pB[k];
            } else if (c == 14) {
                *(float4*)(orow + colb) = pA[k];
                float2 v; v.x = pB[k].x; v.y = pB[k].y;
                *(float2*)(orow + gx0 + 116) = v;
            }
        }
    }
}

extern "C" void kernel_launch(void* const* d_in, const int* in_sizes, int n_in,
                              void* d_out, int out_size, void* d_ws, size_t ws_size,
                              hipStream_t stream) {
    const float* X = (const float*)d_in[0];
    const float* Y = (const float*)d_in[1];
    float* out = (float*)d_out;
    float* ws  = (float*)d_ws;

    // launch 1: init fused + sweeps 1..10 -> ws
    jm_sweep0<<<NTX * NTY, NTHR, 0, stream>>>(X, Y, ws);

    // launches 2..10: sweeps 11..100, ping-pong; 9 launches (odd) -> ends in out
    float* a = ws;
    float* b = out;
    for (int it = 0; it < 9; ++it) {
        jm_sweep<<<NTX * NTY, NTHR, 0, stream>>>(a, b);
        float* tp = a; a = b; b = tp;
    }
}